// Round 1
// baseline (741.570 us; speedup 1.0000x reference)
//
#include <hip/hip_runtime.h>
#include <math.h>

#define F 128
#define NTOT 2080
#define CN 2048
#define AN 16
#define NA 17   // max agents (step>0)

__device__ __forceinline__ float wmax(float v){
  #pragma unroll
  for(int m=32;m;m>>=1) v = fmaxf(v, __shfl_xor(v, m, 64));
  return v;
}
__device__ __forceinline__ float wsum(float v){
  #pragma unroll
  for(int m=32;m;m>>=1) v += __shfl_xor(v, m, 64);
  return v;
}

// K1: per (b, feature j): segment max/mean over N=2080 (city 2048 | a_start 16 | a_end 16)
__global__ __launch_bounds__(256) void k1_reduce(const float* __restrict__ nf,
                                                 float* __restrict__ glb, float* __restrict__ ave){
  const int j = blockIdx.x, b = blockIdx.y, tid = threadIdx.x;
  const float4* row = (const float4*)(nf + (size_t)(b*F + j)*NTOT);
  float cmax=-INFINITY, csum=0.f, smax=-INFINITY, ssum=0.f, emax=-INFINITY, esum=0.f;
  for(int n4 = tid; n4 < 520; n4 += 256){
    float4 v = row[n4];
    float mx = fmaxf(fmaxf(v.x,v.y), fmaxf(v.z,v.w));
    float sm = (v.x+v.y)+(v.z+v.w);
    if(n4 < 512){ cmax=fmaxf(cmax,mx); csum+=sm; }
    else if(n4 < 516){ smax=fmaxf(smax,mx); ssum+=sm; }
    else { emax=fmaxf(emax,mx); esum+=sm; }
  }
  __shared__ float red[4][6];
  cmax=wmax(cmax); csum=wsum(csum); smax=wmax(smax); ssum=wsum(ssum); emax=wmax(emax); esum=wsum(esum);
  const int lane = tid&63, wid = tid>>6;
  if(lane==0){ red[wid][0]=cmax; red[wid][1]=csum; red[wid][2]=smax; red[wid][3]=ssum; red[wid][4]=emax; red[wid][5]=esum; }
  __syncthreads();
  if(tid==0){
    float cM=red[0][0], cS=red[0][1], sM=red[0][2], sS=red[0][3], eM=red[0][4], eS=red[0][5];
    for(int w=1;w<4;w++){ cM=fmaxf(cM,red[w][0]); cS+=red[w][1]; sM=fmaxf(sM,red[w][2]); sS+=red[w][3]; eM=fmaxf(eM,red[w][4]); eS+=red[w][5]; }
    const int gb = b*4*F;
    glb[gb + j]       = fmaxf(cM, fmaxf(sM,eM));
    glb[gb + F + j]   = cM;
    glb[gb + 2*F + j] = sM;
    glb[gb + 3*F + j] = eM;
    float tS = cS+sS+eS;
    ave[gb + j]       = tS / 2080.f;
    ave[gb + F + j]   = cS / 2048.f;
    ave[gb + 2*F + j] = sS / 16.f;
    ave[gb + 3*F + j] = eS / 16.f;
  }
}

// K2: per-batch prep: deglb, free_agent, cvec, af (17x128), afx=af@Wcx2, sx, constpy, constz
__global__ __launch_bounds__(256) void k2_prep(
    const float* __restrict__ nf, const float* __restrict__ Wg, const float* __restrict__ bg,
    const float* __restrict__ Wc, const float* __restrict__ bc,
    const float* __restrict__ Wa, const float* __restrict__ ba,
    const float* __restrict__ Wp, const float* __restrict__ bp,
    const float* __restrict__ glb, const float* __restrict__ ave,
    float* __restrict__ afx, float* __restrict__ sx,
    float* __restrict__ constz, float* __restrict__ constpy){
  const int b = blockIdx.x, tid = threadIdx.x;
  __shared__ float glb_s[4*F], ave_s[4*F], deglb_s[F], fa_s[F];
  __shared__ float asae_s[F*32];   // [feature j][agent col a] : a<16 = a_start, a>=16 = a_end
  __shared__ float af_s[NA*F];
  __shared__ float cvec_s[3*F];
  for(int i=tid;i<4*F;i+=256){ glb_s[i]=glb[b*4*F+i]; ave_s[i]=ave[b*4*F+i]; }
  for(int idx=tid; idx<F*32; idx+=256)
    asae_s[idx] = nf[(size_t)(b*F + (idx>>5))*NTOT + CN + (idx&31)];
  __syncthreads();
  { // deglb (threads 0..127 from glb) and free_agent (128..255 from ave)
    const int j = tid & 127;
    const float* src = (tid<128)? glb_s : ave_s;
    float acc = bg[j];
    const float* wr = Wg + (size_t)j*512;
    for(int k=0;k<512;k++) acc += wr[k]*src[k];
    if(tid<128) deglb_s[j]=acc; else fa_s[j]=acc;
  }
  __syncthreads();
  // cvec[i] = bc[i] + Wc[i, :128] . deglb   (i < 384)
  for(int i=tid;i<3*F;i+=256){
    float acc = bc[i];
    const float* wr = Wc + (size_t)i*256;
    for(int k=0;k<F;k++) acc += wr[k]*deglb_s[k];
    cvec_s[i]=acc;
  }
  { // af[a][j], a<16: thread = (j, group g of 8 agents)
    const int j = tid&127, g = tid>>7;
    const float* wr = Wa + (size_t)j*384;
    float s0 = ba[j];
    for(int k=0;k<F;k++) s0 += wr[k]*deglb_s[k];
    float acc[8];
    #pragma unroll
    for(int i=0;i<8;i++) acc[i]=s0;
    for(int k=0;k<F;k++){
      float w1 = wr[128+k], w2 = wr[256+k];
      const float* as = &asae_s[k*32 + g*8];
      #pragma unroll
      for(int i=0;i<8;i++) acc[i] += w1*as[i] + w2*as[16+i];
    }
    #pragma unroll
    for(int i=0;i<8;i++) af_s[(g*8+i)*F + j] = acc[i];
  }
  if(tid<F) af_s[16*F + tid] = fa_s[tid];   // free_agent appended (agent 16)
  __syncthreads();
  // afx[a][j] = sum_i af[a][i] * Wc[i, 128+j]   (coalesced Wc rows, af broadcast)
  for(int o=tid;o<NA*F;o+=256){
    const int a=o>>7, j=o&127;
    float acc=0.f;
    for(int i=0;i<F;i++) acc += af_s[a*F+i]*Wc[(size_t)i*256+128+j];
    afx[(size_t)b*NA*F + o]=acc;
  }
  if(tid<NA){ // sx[a] = af[a] . constx (cvec[0:128])
    float acc=0.f;
    for(int i=0;i<F;i++) acc += af_s[tid*F+i]*cvec_s[i];
    sx[b*NA+tid]=acc;
  }
  if(tid<F){ // constpy = bp + Wp @ consty ; constz = cvec[256:384]
    float acc = bp[tid];
    const float* wr = Wp + (size_t)tid*128;
    for(int k=0;k<F;k++) acc += wr[k]*cvec_s[128+k];
    constpy[b*F+tid]=acc;
    constz[b*F+tid]=cvec_s[256+tid];
  }
}

// K3: ucj[b,a,c] = (afx[a].city[c] + sx[a])*scale ; per-chunk max -> pmax
__global__ __launch_bounds__(256) void k3_scores(const float* __restrict__ nf, const float* __restrict__ afx,
      const float* __restrict__ sx, float* __restrict__ ucj, float* __restrict__ pmax){
  const int b = blockIdx.y, tid = threadIdx.x;
  const int c = blockIdx.x*256 + tid;
  __shared__ float afx_s[NA*F]; __shared__ float sx_s[NA];
  for(int o=tid;o<NA*F;o+=256) afx_s[o]=afx[(size_t)b*NA*F+o];
  if(tid<NA) sx_s[tid]=sx[b*NA+tid];
  __syncthreads();
  float acc[NA];
  #pragma unroll
  for(int a=0;a<NA;a++) acc[a]=0.f;
  const float* base = nf + (size_t)b*F*NTOT + c;
  #pragma unroll 4
  for(int i=0;i<F;i++){
    float v = base[(size_t)i*NTOT];
    #pragma unroll
    for(int a=0;a<NA;a++) acc[a] += afx_s[a*F+i]*v;
  }
  const float scale = 0.088388347648318447f;
  float uc[NA];
  #pragma unroll
  for(int a=0;a<NA;a++){
    uc[a] = (acc[a]+sx_s[a])*scale;
    ucj[((size_t)b*NA + a)*CN + c] = uc[a];
  }
  __shared__ float red[4][NA];
  const int lane = tid&63, wid = tid>>6;
  #pragma unroll
  for(int a=0;a<NA;a++){
    float m = wmax(uc[a]);
    if(lane==0) red[wid][a]=m;
  }
  __syncthreads();
  if(tid<NA){
    float m = fmaxf(fmaxf(red[0][tid],red[1][tid]), fmaxf(red[2][tid],red[3][tid]));
    pmax[(b*NA+tid)*8 + blockIdx.x] = m;
  }
}

// K4: row softmax (in place exp), rowsum; also zero t
__global__ __launch_bounds__(256) void k4_softmax(float* __restrict__ ucj, const float* __restrict__ pmax,
        float* __restrict__ rowsum, float* __restrict__ t){
  const int a = blockIdx.x, b = blockIdx.y, tid = threadIdx.x;
  if(tid<F) t[((size_t)b*NA+a)*F + tid] = 0.f;
  float m=-INFINITY;
  #pragma unroll
  for(int k=0;k<8;k++) m = fmaxf(m, pmax[(b*NA+a)*8+k]);
  float* row = ucj + ((size_t)b*NA+a)*CN;
  float s=0.f;
  for(int c=tid;c<CN;c+=256){ float e = __expf(row[c]-m); row[c]=e; s+=e; }
  s = wsum(s);
  __shared__ float red[4];
  const int lane=tid&63, wid=tid>>6;
  if(lane==0) red[wid]=s;
  __syncthreads();
  if(tid==0) rowsum[b*NA+a]=red[0]+red[1]+red[2]+red[3];
}

// K5: t[b,a,i] += sum_{c in chunk} attn[a,c]*NF[i,c]  (LDS tiled, atomic partials)
__global__ __launch_bounds__(256) void k5_taccum(const float* __restrict__ nf,
      const float* __restrict__ attn, float* __restrict__ t){
  const int b = blockIdx.y, tid = threadIdx.x;
  const int c0 = blockIdx.x*256;
  __shared__ float nf_s[F*65];     // [i][cc] 64-city sub-tile (pad 65 -> conflict-free)
  __shared__ float at_s[64*20];    // [cc][a] (pad 20)
  __shared__ float part[NA*F];
  const int i = tid&127, h = tid>>7;
  float acc[NA];
  #pragma unroll
  for(int a=0;a<NA;a++) acc[a]=0.f;
  for(int s4=0;s4<4;s4++){
    const int cs = c0 + s4*64;
    for(int idx=tid; idx<F*16; idx+=256){
      const int ii=idx>>4, c4=idx&15;
      float4 v = *(const float4*)(nf + (size_t)(b*F+ii)*NTOT + cs + c4*4);
      float* dst = &nf_s[ii*65 + c4*4];
      dst[0]=v.x; dst[1]=v.y; dst[2]=v.z; dst[3]=v.w;
    }
    for(int idx=tid; idx<NA*64; idx+=256){
      const int a=idx>>6, cc=idx&63;
      at_s[cc*20+a] = attn[((size_t)b*NA+a)*CN + cs + cc];
    }
    __syncthreads();
    for(int cc=h*32; cc<h*32+32; cc++){
      float v = nf_s[i*65+cc];
      const float* at = &at_s[cc*20];
      #pragma unroll
      for(int a=0;a<NA;a++) acc[a] += at[a]*v;
    }
    __syncthreads();
  }
  if(h==1){
    #pragma unroll
    for(int a=0;a<NA;a++) part[a*F+i]=acc[a];
  }
  __syncthreads();
  if(h==0){
    #pragma unroll
    for(int a=0;a<NA;a++) atomicAdd(&t[((size_t)b*NA+a)*F+i], acc[a]+part[a*F+i]);
  }
}

// K5b: per-batch: tn = t/rowsum; u = Wcy2@tn; faf = Wp@u + constpy; afz = Wcz2^T@faf; sz = faf.constz
__global__ __launch_bounds__(256) void k5b_final(const float* __restrict__ Wc, const float* __restrict__ Wp,
      const float* __restrict__ t, const float* __restrict__ rowsum,
      const float* __restrict__ constpy, const float* __restrict__ constz,
      float* __restrict__ afz, float* __restrict__ szv){
  const int b = blockIdx.x, tid = threadIdx.x;
  __shared__ float tn_s[NA*F], u_s[NA*F], faf_s[NA*F];
  __shared__ float cpy_s[F], cz_s[F], rs_s[NA];
  if(tid<NA) rs_s[tid]=rowsum[b*NA+tid];
  if(tid<F){ cpy_s[tid]=constpy[b*F+tid]; cz_s[tid]=constz[b*F+tid]; }
  __syncthreads();
  for(int o=tid;o<NA*F;o+=256) tn_s[o] = t[(size_t)b*NA*F+o] / rs_s[o>>7];
  __syncthreads();
  for(int o=tid;o<NA*F;o+=256){          // u[a,j] = sum_i Wc[128+j, 128+i] * tn[a,i]
    const int a=o>>7, j=o&127;
    float acc=0.f;
    const float* wr = Wc + (size_t)(128+j)*256 + 128;
    for(int i=0;i<F;i++) acc += wr[i]*tn_s[a*F+i];
    u_s[o]=acc;
  }
  __syncthreads();
  for(int o=tid;o<NA*F;o+=256){          // faf[a,jj] = cpy[jj] + sum_j Wp[jj,j]*u[a,j]
    const int a=o>>7, jj=o&127;
    float acc=cpy_s[jj];
    const float* wr = Wp + (size_t)jj*128;
    for(int j=0;j<F;j++) acc += wr[j]*u_s[a*F+j];
    faf_s[o]=acc;
  }
  __syncthreads();
  for(int o=tid;o<NA*F;o+=256){          // afz[a,jc] = sum_k faf[a,k]*Wc[256+k, 128+jc]
    const int a=o>>7, jc=o&127;
    float acc=0.f;
    for(int k=0;k<F;k++) acc += faf_s[a*F+k]*Wc[(size_t)(256+k)*256+128+jc];
    afz[(size_t)b*NA*F+o]=acc;
  }
  if(tid<NA){
    float acc=0.f;
    for(int k=0;k<F;k++) acc += faf_s[tid*F+k]*cz_s[k];
    szv[b*NA+tid]=acc;
  }
}

// K6: logits = tanh((afz.city + sz)*scale)*10 ; softmax over agents; out[b,c,a]
__global__ __launch_bounds__(256) void k6_out(const float* __restrict__ nf, const float* __restrict__ afz,
      const float* __restrict__ szv, const int* __restrict__ step, float* __restrict__ out){
  const int b = blockIdx.y, tid = threadIdx.x;
  const int c = blockIdx.x*256 + tid;
  __shared__ float afz_s[NA*F]; __shared__ float sz_s[NA];
  for(int o=tid;o<NA*F;o+=256) afz_s[o]=afz[(size_t)b*NA*F+o];
  if(tid<NA) sz_s[tid]=szv[b*NA+tid];
  __syncthreads();
  const int A = (step[0] > 0) ? NA : AN;
  float acc[NA];
  #pragma unroll
  for(int a=0;a<NA;a++) acc[a]=0.f;
  const float* base = nf + (size_t)b*F*NTOT + c;
  #pragma unroll 4
  for(int i=0;i<F;i++){
    float v = base[(size_t)i*NTOT];
    #pragma unroll
    for(int a=0;a<NA;a++) acc[a] += afz_s[a*F+i]*v;
  }
  const float scale = 0.088388347648318447f;
  float l[NA];
  #pragma unroll
  for(int a=0;a<NA;a++) l[a] = tanhf((acc[a]+sz_s[a])*scale)*10.f;
  const bool f17 = (A==NA);
  float m = l[0];
  #pragma unroll
  for(int a=1;a<AN;a++) m = fmaxf(m,l[a]);
  if(f17) m = fmaxf(m,l[16]);
  float ssum=0.f;
  #pragma unroll
  for(int a=0;a<AN;a++){ float e=__expf(l[a]-m); l[a]=e; ssum+=e; }
  float e16=__expf(l[16]-m);
  if(f17){ ssum+=e16; }
  const float inv = 1.f/ssum;
  float* op = out + (size_t)(b*CN + c)*A;
  #pragma unroll
  for(int a=0;a<AN;a++) op[a]=l[a]*inv;
  if(f17) op[16]=e16*inv;
}

extern "C" void kernel_launch(void* const* d_in, const int* in_sizes, int n_in,
                              void* d_out, int out_size, void* d_ws, size_t ws_size,
                              hipStream_t stream){
  const float* nf = (const float*)d_in[0];
  const float* Wg = (const float*)d_in[1];
  const float* bg = (const float*)d_in[2];
  const float* Wc = (const float*)d_in[3];
  const float* bc = (const float*)d_in[4];
  const float* Wa = (const float*)d_in[5];
  const float* ba = (const float*)d_in[6];
  const float* Wp = (const float*)d_in[7];
  const float* bp = (const float*)d_in[8];
  const int*  step = (const int*)d_in[9];
  float* out = (float*)d_out;

  float* ws = (float*)d_ws;
  float* glb     = ws;                    // 64*512
  float* ave     = glb + 64*512;          // 64*512
  float* afx     = ave + 64*512;          // 64*17*128
  float* sx      = afx + 64*NA*F;         // 64*17
  float* constz  = sx + 64*NA;            // 64*128
  float* constpy = constz + 64*F;         // 64*128
  float* rowsum  = constpy + 64*F;        // 64*17
  float* t       = rowsum + 64*NA;        // 64*17*128
  float* afz     = t + 64*NA*F;           // 64*17*128
  float* szv     = afz + 64*NA*F;         // 64*17
  float* ucj     = szv + 64*NA;           // 64*17*2048
  float* pmax    = ucj + (size_t)64*NA*CN;// 64*17*8
  // total ~10.5 MiB of ws

  k1_reduce<<<dim3(128,64),256,0,stream>>>(nf, glb, ave);
  k2_prep<<<64,256,0,stream>>>(nf, Wg,bg,Wc,bc,Wa,ba,Wp,bp, glb,ave, afx,sx,constz,constpy);
  k3_scores<<<dim3(8,64),256,0,stream>>>(nf, afx, sx, ucj, pmax);
  k4_softmax<<<dim3(NA,64),256,0,stream>>>(ucj, pmax, rowsum, t);
  k5_taccum<<<dim3(8,64),256,0,stream>>>(nf, ucj, t);
  k5b_final<<<64,256,0,stream>>>(Wc, Wp, t, rowsum, constpy, constz, afz, szv);
  k6_out<<<dim3(8,64),256,0,stream>>>(nf, afz, szv, step, out);
}

// Round 2
// 231.540 us; speedup vs baseline: 3.2028x; 3.2028x over previous
//
#include <hip/hip_runtime.h>
#include <math.h>

#define F 128
#define NTOT 2080
#define CN 2048
#define AN 16
#define NA 17   // max agents (step>0)

__device__ __forceinline__ float wmax(float v){
  #pragma unroll
  for(int m=32;m;m>>=1) v = fmaxf(v, __shfl_xor(v, m, 64));
  return v;
}
__device__ __forceinline__ float wsum(float v){
  #pragma unroll
  for(int m=32;m;m>>=1) v += __shfl_xor(v, m, 64);
  return v;
}

// K1: per (b, feature j): segment max/mean over N=2080 (city 2048 | a_start 16 | a_end 16)
__global__ __launch_bounds__(256) void k1_reduce(const float* __restrict__ nf,
                                                 float* __restrict__ glb, float* __restrict__ ave){
  const int j = blockIdx.x, b = blockIdx.y, tid = threadIdx.x;
  const float4* row = (const float4*)(nf + (size_t)(b*F + j)*NTOT);
  float cmax=-INFINITY, csum=0.f, smax=-INFINITY, ssum=0.f, emax=-INFINITY, esum=0.f;
  for(int n4 = tid; n4 < 520; n4 += 256){
    float4 v = row[n4];
    float mx = fmaxf(fmaxf(v.x,v.y), fmaxf(v.z,v.w));
    float sm = (v.x+v.y)+(v.z+v.w);
    if(n4 < 512){ cmax=fmaxf(cmax,mx); csum+=sm; }
    else if(n4 < 516){ smax=fmaxf(smax,mx); ssum+=sm; }
    else { emax=fmaxf(emax,mx); esum+=sm; }
  }
  __shared__ float red[4][6];
  cmax=wmax(cmax); csum=wsum(csum); smax=wmax(smax); ssum=wsum(ssum); emax=wmax(emax); esum=wsum(esum);
  const int lane = tid&63, wid = tid>>6;
  if(lane==0){ red[wid][0]=cmax; red[wid][1]=csum; red[wid][2]=smax; red[wid][3]=ssum; red[wid][4]=emax; red[wid][5]=esum; }
  __syncthreads();
  if(tid==0){
    float cM=red[0][0], cS=red[0][1], sM=red[0][2], sS=red[0][3], eM=red[0][4], eS=red[0][5];
    for(int w=1;w<4;w++){ cM=fmaxf(cM,red[w][0]); cS+=red[w][1]; sM=fmaxf(sM,red[w][2]); sS+=red[w][3]; eM=fmaxf(eM,red[w][4]); eS+=red[w][5]; }
    const int gb = b*4*F;
    glb[gb + j]       = fmaxf(cM, fmaxf(sM,eM));
    glb[gb + F + j]   = cM;
    glb[gb + 2*F + j] = sM;
    glb[gb + 3*F + j] = eM;
    float tS = cS+sS+eS;
    ave[gb + j]       = tS / 2080.f;
    ave[gb + F + j]   = cS / 2048.f;
    ave[gb + 2*F + j] = sS / 16.f;
    ave[gb + 3*F + j] = eS / 16.f;
  }
}

// K2: per-batch prep: deglb, free_agent, cvec, af (17x128), afx=af@Wcx2, sx, constpy, constz
__global__ __launch_bounds__(256) void k2_prep(
    const float* __restrict__ nf, const float* __restrict__ Wg, const float* __restrict__ bg,
    const float* __restrict__ Wc, const float* __restrict__ bc,
    const float* __restrict__ Wa, const float* __restrict__ ba,
    const float* __restrict__ Wp, const float* __restrict__ bp,
    const float* __restrict__ glb, const float* __restrict__ ave,
    float* __restrict__ afx, float* __restrict__ sx,
    float* __restrict__ constz, float* __restrict__ constpy){
  const int b = blockIdx.x, tid = threadIdx.x;
  __shared__ float glb_s[4*F], ave_s[4*F], deglb_s[F], fa_s[F];
  __shared__ float asae_s[F*32];   // [feature j][agent col a] : a<16 = a_start, a>=16 = a_end
  __shared__ float af_s[NA*F];
  __shared__ float cvec_s[3*F];
  for(int i=tid;i<4*F;i+=256){ glb_s[i]=glb[b*4*F+i]; ave_s[i]=ave[b*4*F+i]; }
  for(int idx=tid; idx<F*32; idx+=256)
    asae_s[idx] = nf[(size_t)(b*F + (idx>>5))*NTOT + CN + (idx&31)];
  __syncthreads();
  { // deglb (threads 0..127 from glb) and free_agent (128..255 from ave)
    const int j = tid & 127;
    const float* src = (tid<128)? glb_s : ave_s;
    float acc = bg[j];
    const float* wr = Wg + (size_t)j*512;
    for(int k=0;k<512;k++) acc += wr[k]*src[k];
    if(tid<128) deglb_s[j]=acc; else fa_s[j]=acc;
  }
  __syncthreads();
  // cvec[i] = bc[i] + Wc[i, :128] . deglb   (i < 384)
  for(int i=tid;i<3*F;i+=256){
    float acc = bc[i];
    const float* wr = Wc + (size_t)i*256;
    for(int k=0;k<F;k++) acc += wr[k]*deglb_s[k];
    cvec_s[i]=acc;
  }
  { // af[a][j], a<16: thread = (j, group g of 8 agents)
    const int j = tid&127, g = tid>>7;
    const float* wr = Wa + (size_t)j*384;
    float s0 = ba[j];
    for(int k=0;k<F;k++) s0 += wr[k]*deglb_s[k];
    float acc[8];
    #pragma unroll
    for(int i=0;i<8;i++) acc[i]=s0;
    for(int k=0;k<F;k++){
      float w1 = wr[128+k], w2 = wr[256+k];
      const float* as = &asae_s[k*32 + g*8];
      #pragma unroll
      for(int i=0;i<8;i++) acc[i] += w1*as[i] + w2*as[16+i];
    }
    #pragma unroll
    for(int i=0;i<8;i++) af_s[(g*8+i)*F + j] = acc[i];
  }
  if(tid<F) af_s[16*F + tid] = fa_s[tid];   // free_agent appended (agent 16)
  __syncthreads();
  // afx[a][j] = sum_i af[a][i] * Wc[i, 128+j]   (coalesced Wc rows, af broadcast)
  for(int o=tid;o<NA*F;o+=256){
    const int a=o>>7, j=o&127;
    float acc=0.f;
    for(int i=0;i<F;i++) acc += af_s[a*F+i]*Wc[(size_t)i*256+128+j];
    afx[(size_t)b*NA*F + o]=acc;
  }
  if(tid<NA){ // sx[a] = af[a] . constx (cvec[0:128])
    float acc=0.f;
    for(int i=0;i<F;i++) acc += af_s[tid*F+i]*cvec_s[i];
    sx[b*NA+tid]=acc;
  }
  if(tid<F){ // constpy = bp + Wp @ consty ; constz = cvec[256:384]
    float acc = bp[tid];
    const float* wr = Wp + (size_t)tid*128;
    for(int k=0;k<F;k++) acc += wr[k]*cvec_s[128+k];
    constpy[b*F+tid]=acc;
    constz[b*F+tid]=cvec_s[256+tid];
  }
}

// K3: ucj[b,a,c] = (afx[a].city[c] + sx[a])*scale ; per-chunk max -> pmax
__global__ __launch_bounds__(256) void k3_scores(const float* __restrict__ nf, const float* __restrict__ afx,
      const float* __restrict__ sx, float* __restrict__ ucj, float* __restrict__ pmax){
  const int b = blockIdx.y, tid = threadIdx.x;
  const int c = blockIdx.x*256 + tid;
  __shared__ float afx_s[NA*F]; __shared__ float sx_s[NA];
  for(int o=tid;o<NA*F;o+=256) afx_s[o]=afx[(size_t)b*NA*F+o];
  if(tid<NA) sx_s[tid]=sx[b*NA+tid];
  __syncthreads();
  float acc[NA];
  #pragma unroll
  for(int a=0;a<NA;a++) acc[a]=0.f;
  const float* base = nf + (size_t)b*F*NTOT + c;
  #pragma unroll 4
  for(int i=0;i<F;i++){
    float v = base[(size_t)i*NTOT];
    #pragma unroll
    for(int a=0;a<NA;a++) acc[a] += afx_s[a*F+i]*v;
  }
  const float scale = 0.088388347648318447f;
  float uc[NA];
  #pragma unroll
  for(int a=0;a<NA;a++){
    uc[a] = (acc[a]+sx_s[a])*scale;
    ucj[((size_t)b*NA + a)*CN + c] = uc[a];
  }
  __shared__ float red[4][NA];
  const int lane = tid&63, wid = tid>>6;
  #pragma unroll
  for(int a=0;a<NA;a++){
    float m = wmax(uc[a]);
    if(lane==0) red[wid][a]=m;
  }
  __syncthreads();
  if(tid<NA){
    float m = fmaxf(fmaxf(red[0][tid],red[1][tid]), fmaxf(red[2][tid],red[3][tid]));
    pmax[(b*NA+tid)*8 + blockIdx.x] = m;
  }
}

// K4: row softmax (in place exp), rowsum
__global__ __launch_bounds__(256) void k4_softmax(float* __restrict__ ucj, const float* __restrict__ pmax,
        float* __restrict__ rowsum){
  const int a = blockIdx.x, b = blockIdx.y, tid = threadIdx.x;
  float m=-INFINITY;
  #pragma unroll
  for(int k=0;k<8;k++) m = fmaxf(m, pmax[(b*NA+a)*8+k]);
  float* row = ucj + ((size_t)b*NA+a)*CN;
  float s=0.f;
  for(int c=tid;c<CN;c+=256){ float e = __expf(row[c]-m); row[c]=e; s+=e; }
  s = wsum(s);
  __shared__ float red[4];
  const int lane=tid&63, wid=tid>>6;
  if(lane==0) red[wid]=s;
  __syncthreads();
  if(tid==0) rowsum[b*NA+a]=red[0]+red[1]+red[2]+red[3];
}

// K5: tpart[chunk][b][a][i] = sum_{c in chunk} attn[a,c]*nf[i,c]
// agents split across thread-halves: h=0 -> a 0..8, h=1 -> a 8..16 (overlap at 8,
// h=1 skips writing a=8) so both inner loops are constant-trip 9 -> ~30 VGPRs, no spill.
__global__ __launch_bounds__(256) void k5_taccum(const float* __restrict__ nf,
      const float* __restrict__ attn, float* __restrict__ tpart){
  const int b = blockIdx.y, tid = threadIdx.x;
  const int c0 = blockIdx.x*256;
  __shared__ float4 nf4_s[F*16];    // swizzled: [i][g ^ (i&15)]
  __shared__ float4 at4_s[NA*16];   // [a][g] for current 64-city subtile
  const int i = tid&127, h = tid>>7;
  const int A0 = h*8;
  float acc[9];
  #pragma unroll
  for(int a=0;a<9;a++) acc[a]=0.f;
  for(int s4=0;s4<4;s4++){
    const int cs = c0 + s4*64;
    __syncthreads();   // previous subtile's reads done before overwrite
    for(int idx=tid; idx<F*16; idx+=256){
      const int ii=idx>>4, g=idx&15;
      nf4_s[ii*16 + (g^(ii&15))] = *(const float4*)(nf + (size_t)(b*F+ii)*NTOT + cs + g*4);
    }
    for(int idx=tid; idx<NA*16; idx+=256){
      const int a=idx>>4, g=idx&15;
      at4_s[idx] = *(const float4*)(attn + ((size_t)b*NA+a)*CN + cs + g*4);
    }
    __syncthreads();
    #pragma unroll 2
    for(int g=0; g<16; g++){
      float4 v = nf4_s[i*16 + (g^(i&15))];
      #pragma unroll
      for(int a=0;a<9;a++){
        float4 w = at4_s[(A0+a)*16+g];
        acc[a] += w.x*v.x + w.y*v.y + w.z*v.z + w.w*v.w;
      }
    }
  }
  float* dst = tpart + (size_t)blockIdx.x*64*NA*F + (size_t)b*NA*F;
  #pragma unroll
  for(int a=0;a<9;a++){
    if(h==0 || a>0) dst[(A0+a)*F + i] = acc[a];
  }
}

// K5b: per-batch: tn = (sum_k tpart[k])/rowsum; u = Wcy2@tn; faf = Wp@u + constpy; afz = Wcz2^T@faf; sz = faf.constz
__global__ __launch_bounds__(256) void k5b_final(const float* __restrict__ Wc, const float* __restrict__ Wp,
      const float* __restrict__ tpart, const float* __restrict__ rowsum,
      const float* __restrict__ constpy, const float* __restrict__ constz,
      float* __restrict__ afz, float* __restrict__ szv){
  const int b = blockIdx.x, tid = threadIdx.x;
  __shared__ float tn_s[NA*F], u_s[NA*F], faf_s[NA*F];
  __shared__ float cpy_s[F], cz_s[F], rs_s[NA];
  if(tid<NA) rs_s[tid]=rowsum[b*NA+tid];
  if(tid<F){ cpy_s[tid]=constpy[b*F+tid]; cz_s[tid]=constz[b*F+tid]; }
  __syncthreads();
  for(int o=tid;o<NA*F;o+=256){
    float s=0.f;
    #pragma unroll
    for(int k=0;k<8;k++) s += tpart[(size_t)k*64*NA*F + (size_t)b*NA*F + o];
    tn_s[o] = s / rs_s[o>>7];
  }
  __syncthreads();
  for(int o=tid;o<NA*F;o+=256){          // u[a,j] = sum_i Wc[128+j, 128+i] * tn[a,i]
    const int a=o>>7, j=o&127;
    float acc=0.f;
    const float* wr = Wc + (size_t)(128+j)*256 + 128;
    for(int i=0;i<F;i++) acc += wr[i]*tn_s[a*F+i];
    u_s[o]=acc;
  }
  __syncthreads();
  for(int o=tid;o<NA*F;o+=256){          // faf[a,jj] = cpy[jj] + sum_j Wp[jj,j]*u[a,j]
    const int a=o>>7, jj=o&127;
    float acc=cpy_s[jj];
    const float* wr = Wp + (size_t)jj*128;
    for(int j=0;j<F;j++) acc += wr[j]*u_s[a*F+j];
    faf_s[o]=acc;
  }
  __syncthreads();
  for(int o=tid;o<NA*F;o+=256){          // afz[a,jc] = sum_k faf[a,k]*Wc[256+k, 128+jc]
    const int a=o>>7, jc=o&127;
    float acc=0.f;
    for(int k=0;k<F;k++) acc += faf_s[a*F+k]*Wc[(size_t)(256+k)*256+128+jc];
    afz[(size_t)b*NA*F+o]=acc;
  }
  if(tid<NA){
    float acc=0.f;
    for(int k=0;k<F;k++) acc += faf_s[tid*F+k]*cz_s[k];
    szv[b*NA+tid]=acc;
  }
}

// K6: logits = tanh((afz.city + sz)*scale)*10 ; softmax over agents; out[b,c,a]
__global__ __launch_bounds__(256) void k6_out(const float* __restrict__ nf, const float* __restrict__ afz,
      const float* __restrict__ szv, const int* __restrict__ step, float* __restrict__ out){
  const int b = blockIdx.y, tid = threadIdx.x;
  const int c = blockIdx.x*256 + tid;
  __shared__ float afz_s[NA*F]; __shared__ float sz_s[NA];
  for(int o=tid;o<NA*F;o+=256) afz_s[o]=afz[(size_t)b*NA*F+o];
  if(tid<NA) sz_s[tid]=szv[b*NA+tid];
  __syncthreads();
  const int A = (step[0] > 0) ? NA : AN;
  float acc[NA];
  #pragma unroll
  for(int a=0;a<NA;a++) acc[a]=0.f;
  const float* base = nf + (size_t)b*F*NTOT + c;
  #pragma unroll 4
  for(int i=0;i<F;i++){
    float v = base[(size_t)i*NTOT];
    #pragma unroll
    for(int a=0;a<NA;a++) acc[a] += afz_s[a*F+i]*v;
  }
  const float scale = 0.088388347648318447f;
  float l[NA];
  #pragma unroll
  for(int a=0;a<NA;a++) l[a] = tanhf((acc[a]+sz_s[a])*scale)*10.f;
  const bool f17 = (A==NA);
  float m = l[0];
  #pragma unroll
  for(int a=1;a<AN;a++) m = fmaxf(m,l[a]);
  if(f17) m = fmaxf(m,l[16]);
  float ssum=0.f;
  #pragma unroll
  for(int a=0;a<AN;a++){ float e=__expf(l[a]-m); l[a]=e; ssum+=e; }
  float e16=__expf(l[16]-m);
  if(f17){ ssum+=e16; }
  const float inv = 1.f/ssum;
  float* op = out + (size_t)(b*CN + c)*A;
  #pragma unroll
  for(int a=0;a<AN;a++) op[a]=l[a]*inv;
  if(f17) op[16]=e16*inv;
}

extern "C" void kernel_launch(void* const* d_in, const int* in_sizes, int n_in,
                              void* d_out, int out_size, void* d_ws, size_t ws_size,
                              hipStream_t stream){
  const float* nf = (const float*)d_in[0];
  const float* Wg = (const float*)d_in[1];
  const float* bg = (const float*)d_in[2];
  const float* Wc = (const float*)d_in[3];
  const float* bc = (const float*)d_in[4];
  const float* Wa = (const float*)d_in[5];
  const float* ba = (const float*)d_in[6];
  const float* Wp = (const float*)d_in[7];
  const float* bp = (const float*)d_in[8];
  const int*  step = (const int*)d_in[9];
  float* out = (float*)d_out;

  float* ws = (float*)d_ws;
  float* glb     = ws;                    // 64*512
  float* ave     = glb + 64*512;          // 64*512
  float* afx     = ave + 64*512;          // 64*17*128
  float* sx      = afx + 64*NA*F;         // 64*17
  float* constz  = sx + 64*NA;            // 64*128
  float* constpy = constz + 64*F;         // 64*128
  float* rowsum  = constpy + 64*F;        // 64*17
  float* tpart   = rowsum + 64*NA;        // 8*64*17*128
  float* afz     = tpart + 8*64*NA*F;     // 64*17*128
  float* szv     = afz + 64*NA*F;         // 64*17
  float* ucj     = szv + 64*NA;           // 64*17*2048
  float* pmax    = ucj + (size_t)64*NA*CN;// 64*17*8
  // total ~14.9 MiB of ws

  k1_reduce<<<dim3(128,64),256,0,stream>>>(nf, glb, ave);
  k2_prep<<<64,256,0,stream>>>(nf, Wg,bg,Wc,bc,Wa,ba,Wp,bp, glb,ave, afx,sx,constz,constpy);
  k3_scores<<<dim3(8,64),256,0,stream>>>(nf, afx, sx, ucj, pmax);
  k4_softmax<<<dim3(NA,64),256,0,stream>>>(ucj, pmax, rowsum);
  k5_taccum<<<dim3(8,64),256,0,stream>>>(nf, ucj, tpart);
  k5b_final<<<64,256,0,stream>>>(Wc, Wp, tpart, rowsum, constpy, constz, afz, szv);
  k6_out<<<dim3(8,64),256,0,stream>>>(nf, afz, szv, step, out);
}

// Round 3
// 189.036 us; speedup vs baseline: 3.9229x; 1.2248x over previous
//
#include <hip/hip_runtime.h>
#include <math.h>

#define F 128
#define NTOT 2080
#define CN 2048
#define AN 16
#define NA 17   // max agents (step>0)

__device__ __forceinline__ float wmax(float v){
  #pragma unroll
  for(int m=32;m;m>>=1) v = fmaxf(v, __shfl_xor(v, m, 64));
  return v;
}
__device__ __forceinline__ float wsum(float v){
  #pragma unroll
  for(int m=32;m;m>>=1) v += __shfl_xor(v, m, 64);
  return v;
}

// K0a: Wpy = Wp @ Wcy2   (Wpy[k,i] = sum_j Wp[k,j]*Wc[128+j, 128+i])
__global__ __launch_bounds__(128) void k0a_wpy(const float* __restrict__ Wp, const float* __restrict__ Wc,
                                               float* __restrict__ Wpy){
  const int k = blockIdx.x, i = threadIdx.x;
  float acc = 0.f;
  const float* wp = Wp + (size_t)k*F;
  for(int j=0;j<F;j++) acc += wp[j]*Wc[(size_t)(128+j)*256 + 128 + i];
  Wpy[k*F+i] = acc;
}

// K0b: M1 = Wcz2^T @ Wpy  (M1[jc,i] = sum_k Wc[256+k, 128+jc]*Wpy[k,i])
__global__ __launch_bounds__(128) void k0b_m1(const float* __restrict__ Wc, const float* __restrict__ Wpy,
                                              float* __restrict__ M1){
  const int jc = blockIdx.x, i = threadIdx.x;
  float acc = 0.f;
  for(int k=0;k<F;k++) acc += Wc[(size_t)(256+k)*256 + 128 + jc]*Wpy[k*F+i];
  M1[jc*F+i] = acc;
}

// K1: per (b, feature j): segment max/mean over N=2080 (city 2048 | a_start 16 | a_end 16)
__global__ __launch_bounds__(256) void k1_reduce(const float* __restrict__ nf,
                                                 float* __restrict__ glb, float* __restrict__ ave){
  const int j = blockIdx.x, b = blockIdx.y, tid = threadIdx.x;
  const float4* row = (const float4*)(nf + (size_t)(b*F + j)*NTOT);
  float cmax=-INFINITY, csum=0.f, smax=-INFINITY, ssum=0.f, emax=-INFINITY, esum=0.f;
  for(int n4 = tid; n4 < 520; n4 += 256){
    float4 v = row[n4];
    float mx = fmaxf(fmaxf(v.x,v.y), fmaxf(v.z,v.w));
    float sm = (v.x+v.y)+(v.z+v.w);
    if(n4 < 512){ cmax=fmaxf(cmax,mx); csum+=sm; }
    else if(n4 < 516){ smax=fmaxf(smax,mx); ssum+=sm; }
    else { emax=fmaxf(emax,mx); esum+=sm; }
  }
  __shared__ float red[4][6];
  cmax=wmax(cmax); csum=wsum(csum); smax=wmax(smax); ssum=wsum(ssum); emax=wmax(emax); esum=wsum(esum);
  const int lane = tid&63, wid = tid>>6;
  if(lane==0){ red[wid][0]=cmax; red[wid][1]=csum; red[wid][2]=smax; red[wid][3]=ssum; red[wid][4]=emax; red[wid][5]=esum; }
  __syncthreads();
  if(tid==0){
    float cM=red[0][0], cS=red[0][1], sM=red[0][2], sS=red[0][3], eM=red[0][4], eS=red[0][5];
    for(int w=1;w<4;w++){ cM=fmaxf(cM,red[w][0]); cS+=red[w][1]; sM=fmaxf(sM,red[w][2]); sS+=red[w][3]; eM=fmaxf(eM,red[w][4]); eS+=red[w][5]; }
    const int gb = b*4*F;
    glb[gb + j]       = fmaxf(cM, fmaxf(sM,eM));
    glb[gb + F + j]   = cM;
    glb[gb + 2*F + j] = sM;
    glb[gb + 3*F + j] = eM;
    float tS = cS+sS+eS;
    ave[gb + j]       = tS / 2080.f;
    ave[gb + F + j]   = cS / 2048.f;
    ave[gb + 2*F + j] = sS / 16.f;
    ave[gb + 3*F + j] = eS / 16.f;
  }
}

// K2: per-batch prep: deglb, free_agent, cvec, af (17x128), afx=af@Wcx2, sx, czc, vz, szc
__global__ __launch_bounds__(256) void k2_prep(
    const float* __restrict__ nf, const float* __restrict__ Wg, const float* __restrict__ bg,
    const float* __restrict__ Wc, const float* __restrict__ bc,
    const float* __restrict__ Wa, const float* __restrict__ ba,
    const float* __restrict__ Wp, const float* __restrict__ bp,
    const float* __restrict__ Wpy,
    const float* __restrict__ glb, const float* __restrict__ ave,
    float* __restrict__ afx, float* __restrict__ sx,
    float* __restrict__ czc, float* __restrict__ vz, float* __restrict__ szc){
  const int b = blockIdx.x, tid = threadIdx.x;
  __shared__ float glb_s[4*F], ave_s[4*F], deglb_s[F], fa_s[F];
  __shared__ float asae_s[F*32];   // [feature j][agent col a] : a<16 = a_start, a>=16 = a_end
  __shared__ float af_s[NA*F];
  __shared__ float cvec_s[3*F];
  __shared__ float cpy_s[F];
  for(int i=tid;i<4*F;i+=256){ glb_s[i]=glb[b*4*F+i]; ave_s[i]=ave[b*4*F+i]; }
  for(int idx=tid; idx<F*32; idx+=256)
    asae_s[idx] = nf[(size_t)(b*F + (idx>>5))*NTOT + CN + (idx&31)];
  __syncthreads();
  { // deglb (threads 0..127 from glb) and free_agent (128..255 from ave)
    const int j = tid & 127;
    const float* src = (tid<128)? glb_s : ave_s;
    float acc = bg[j];
    const float* wr = Wg + (size_t)j*512;
    for(int k=0;k<512;k++) acc += wr[k]*src[k];
    if(tid<128) deglb_s[j]=acc; else fa_s[j]=acc;
  }
  __syncthreads();
  // cvec[i] = bc[i] + Wc[i, :128] . deglb   (i < 384)
  for(int i=tid;i<3*F;i+=256){
    float acc = bc[i];
    const float* wr = Wc + (size_t)i*256;
    for(int k=0;k<F;k++) acc += wr[k]*deglb_s[k];
    cvec_s[i]=acc;
  }
  { // af[a][j], a<16: thread = (j, group g of 8 agents)
    const int j = tid&127, g = tid>>7;
    const float* wr = Wa + (size_t)j*384;
    float s0 = ba[j];
    for(int k=0;k<F;k++) s0 += wr[k]*deglb_s[k];
    float acc[8];
    #pragma unroll
    for(int i=0;i<8;i++) acc[i]=s0;
    for(int k=0;k<F;k++){
      float w1 = wr[128+k], w2 = wr[256+k];
      const float* as = &asae_s[k*32 + g*8];
      #pragma unroll
      for(int i=0;i<8;i++) acc[i] += w1*as[i] + w2*as[16+i];
    }
    #pragma unroll
    for(int i=0;i<8;i++) af_s[(g*8+i)*F + j] = acc[i];
  }
  if(tid<F) af_s[16*F + tid] = fa_s[tid];   // free_agent appended (agent 16)
  __syncthreads();
  // afx[a][j] = sum_i af[a][i] * Wc[i, 128+j]   (coalesced Wc rows, af broadcast)
  for(int o=tid;o<NA*F;o+=256){
    const int a=o>>7, j=o&127;
    float acc=0.f;
    for(int i=0;i<F;i++) acc += af_s[a*F+i]*Wc[(size_t)i*256+128+j];
    afx[(size_t)b*NA*F + o]=acc;
  }
  if(tid<NA){ // sx[a] = af[a] . constx (cvec[0:128])
    float acc=0.f;
    for(int i=0;i<F;i++) acc += af_s[tid*F+i]*cvec_s[i];
    sx[b*NA+tid]=acc;
  }
  if(tid<F){ // cpy = bp + Wp @ consty
    float acc = bp[tid];
    const float* wr = Wp + (size_t)tid*128;
    for(int k=0;k<F;k++) acc += wr[k]*cvec_s[128+k];
    cpy_s[tid]=acc;
  }
  __syncthreads();
  { // czc[jc] = Wcz2^T @ cpy ; vz[i] = Wpy^T @ cz
    const int j = tid&127;
    if(tid<128){
      float acc=0.f;
      for(int k=0;k<F;k++) acc += Wc[(size_t)(256+k)*256 + 128 + j]*cpy_s[k];
      czc[b*F+j]=acc;
    } else {
      float acc=0.f;
      for(int k=0;k<F;k++) acc += Wpy[k*F+j]*cvec_s[256+k];
      vz[b*F+j]=acc;
    }
  }
  if(tid==0){ // szc = cpy . cz
    float acc=0.f;
    for(int k=0;k<F;k++) acc += cpy_s[k]*cvec_s[256+k];
    szc[b]=acc;
  }
}

// K3: ucj[b,a,c] = (afx[a].city[c] + sx[a])*scale ; per-chunk max -> pmax
__global__ __launch_bounds__(256) void k3_scores(const float* __restrict__ nf, const float* __restrict__ afx,
      const float* __restrict__ sx, float* __restrict__ ucj, float* __restrict__ pmax){
  const int b = blockIdx.y, tid = threadIdx.x;
  const int c = blockIdx.x*256 + tid;
  __shared__ float afx_s[NA*F]; __shared__ float sx_s[NA];
  for(int o=tid;o<NA*F;o+=256) afx_s[o]=afx[(size_t)b*NA*F+o];
  if(tid<NA) sx_s[tid]=sx[b*NA+tid];
  __syncthreads();
  float acc[NA];
  #pragma unroll
  for(int a=0;a<NA;a++) acc[a]=0.f;
  const float* base = nf + (size_t)b*F*NTOT + c;
  #pragma unroll 4
  for(int i=0;i<F;i++){
    float v = base[(size_t)i*NTOT];
    #pragma unroll
    for(int a=0;a<NA;a++) acc[a] += afx_s[a*F+i]*v;
  }
  const float scale = 0.088388347648318447f;
  float uc[NA];
  #pragma unroll
  for(int a=0;a<NA;a++){
    uc[a] = (acc[a]+sx_s[a])*scale;
    ucj[((size_t)b*NA + a)*CN + c] = uc[a];
  }
  __shared__ float red[4][NA];
  const int lane = tid&63, wid = tid>>6;
  #pragma unroll
  for(int a=0;a<NA;a++){
    float m = wmax(uc[a]);
    if(lane==0) red[wid][a]=m;
  }
  __syncthreads();
  if(tid<NA){
    float m = fmaxf(fmaxf(red[0][tid],red[1][tid]), fmaxf(red[2][tid],red[3][tid]));
    pmax[(b*NA+tid)*8 + blockIdx.x] = m;
  }
}

// K4: row softmax (in place exp), rowsum
__global__ __launch_bounds__(256) void k4_softmax(float* __restrict__ ucj, const float* __restrict__ pmax,
        float* __restrict__ rowsum){
  const int a = blockIdx.x, b = blockIdx.y, tid = threadIdx.x;
  float m=-INFINITY;
  #pragma unroll
  for(int k=0;k<8;k++) m = fmaxf(m, pmax[(b*NA+a)*8+k]);
  float* row = ucj + ((size_t)b*NA+a)*CN;
  float s=0.f;
  for(int c=tid;c<CN;c+=256){ float e = __expf(row[c]-m); row[c]=e; s+=e; }
  s = wsum(s);
  __shared__ float red[4];
  const int lane=tid&63, wid=tid>>6;
  if(lane==0) red[wid]=s;
  __syncthreads();
  if(tid==0) rowsum[b*NA+a]=red[0]+red[1]+red[2]+red[3];
}

// K5: tpart[chunk][b][a][i] = sum_{c in chunk} attn[a,c]*nf[i,c]
// agents split across thread-halves: h=0 -> a 0..8, h=1 -> a 8..16 (overlap at 8,
// h=1 skips writing a=8) so both inner loops are constant-trip 9 -> no spill.
__global__ __launch_bounds__(256) void k5_taccum(const float* __restrict__ nf,
      const float* __restrict__ attn, float* __restrict__ tpart){
  const int b = blockIdx.y, tid = threadIdx.x;
  const int c0 = blockIdx.x*256;
  __shared__ float4 nf4_s[F*16];    // swizzled: [i][g ^ (i&15)]
  __shared__ float4 at4_s[NA*16];   // [a][g] for current 64-city subtile
  const int i = tid&127, h = tid>>7;
  const int A0 = h*8;
  float acc[9];
  #pragma unroll
  for(int a=0;a<9;a++) acc[a]=0.f;
  for(int s4=0;s4<4;s4++){
    const int cs = c0 + s4*64;
    __syncthreads();   // previous subtile's reads done before overwrite
    for(int idx=tid; idx<F*16; idx+=256){
      const int ii=idx>>4, g=idx&15;
      nf4_s[ii*16 + (g^(ii&15))] = *(const float4*)(nf + (size_t)(b*F+ii)*NTOT + cs + g*4);
    }
    for(int idx=tid; idx<NA*16; idx+=256){
      const int a=idx>>4, g=idx&15;
      at4_s[idx] = *(const float4*)(attn + ((size_t)b*NA+a)*CN + cs + g*4);
    }
    __syncthreads();
    #pragma unroll 2
    for(int g=0; g<16; g++){
      float4 v = nf4_s[i*16 + (g^(i&15))];
      #pragma unroll
      for(int a=0;a<9;a++){
        float4 w = at4_s[(A0+a)*16+g];
        acc[a] += w.x*v.x + w.y*v.y + w.z*v.z + w.w*v.w;
      }
    }
  }
  float* dst = tpart + (size_t)blockIdx.x*64*NA*F + (size_t)b*NA*F;
  #pragma unroll
  for(int a=0;a<9;a++){
    if(h==0 || a>0) dst[(A0+a)*F + i] = acc[a];
  }
}

// K5b: per (b,a): tn = (sum_k tpart)/rowsum; afz = M1@tn + czc; sz = tn.vz + szc
__global__ __launch_bounds__(128) void k5b_final(const float* __restrict__ M1,
      const float* __restrict__ tpart, const float* __restrict__ rowsum,
      const float* __restrict__ czc, const float* __restrict__ vz, const float* __restrict__ szc,
      float* __restrict__ afz, float* __restrict__ szv){
  const int a = blockIdx.x, b = blockIdx.y, tid = threadIdx.x;
  __shared__ float tn_s[F];
  float s = 0.f;
  #pragma unroll
  for(int k=0;k<8;k++) s += tpart[(size_t)k*64*NA*F + ((size_t)b*NA+a)*F + tid];
  tn_s[tid] = s / rowsum[b*NA+a];
  __syncthreads();
  float acc = 0.f;
  const float* m = M1 + (size_t)tid*F;
  for(int i=0;i<F;i++) acc += m[i]*tn_s[i];
  afz[((size_t)b*NA+a)*F + tid] = acc + czc[b*F+tid];
  float p = tn_s[tid]*vz[b*F+tid];
  p = wsum(p);
  __shared__ float red[2];
  if((tid&63)==0) red[tid>>6]=p;
  __syncthreads();
  if(tid==0) szv[b*NA+a] = red[0]+red[1] + szc[b];
}

// K6: logits = tanh((afz.city + sz)*scale)*10 ; softmax over agents; out[b,c,a]
__global__ __launch_bounds__(256) void k6_out(const float* __restrict__ nf, const float* __restrict__ afz,
      const float* __restrict__ szv, const int* __restrict__ step, float* __restrict__ out){
  const int b = blockIdx.y, tid = threadIdx.x;
  const int c = blockIdx.x*256 + tid;
  __shared__ float afz_s[NA*F]; __shared__ float sz_s[NA];
  for(int o=tid;o<NA*F;o+=256) afz_s[o]=afz[(size_t)b*NA*F+o];
  if(tid<NA) sz_s[tid]=szv[b*NA+tid];
  __syncthreads();
  const int A = (step[0] > 0) ? NA : AN;
  float acc[NA];
  #pragma unroll
  for(int a=0;a<NA;a++) acc[a]=0.f;
  const float* base = nf + (size_t)b*F*NTOT + c;
  #pragma unroll 4
  for(int i=0;i<F;i++){
    float v = base[(size_t)i*NTOT];
    #pragma unroll
    for(int a=0;a<NA;a++) acc[a] += afz_s[a*F+i]*v;
  }
  const float scale = 0.088388347648318447f;
  float l[NA];
  #pragma unroll
  for(int a=0;a<NA;a++) l[a] = tanhf((acc[a]+sz_s[a])*scale)*10.f;
  const bool f17 = (A==NA);
  float m = l[0];
  #pragma unroll
  for(int a=1;a<AN;a++) m = fmaxf(m,l[a]);
  if(f17) m = fmaxf(m,l[16]);
  float ssum=0.f;
  #pragma unroll
  for(int a=0;a<AN;a++){ float e=__expf(l[a]-m); l[a]=e; ssum+=e; }
  float e16=__expf(l[16]-m);
  if(f17){ ssum+=e16; }
  const float inv = 1.f/ssum;
  float* op = out + (size_t)(b*CN + c)*A;
  #pragma unroll
  for(int a=0;a<AN;a++) op[a]=l[a]*inv;
  if(f17) op[16]=e16*inv;
}

extern "C" void kernel_launch(void* const* d_in, const int* in_sizes, int n_in,
                              void* d_out, int out_size, void* d_ws, size_t ws_size,
                              hipStream_t stream){
  const float* nf = (const float*)d_in[0];
  const float* Wg = (const float*)d_in[1];
  const float* bg = (const float*)d_in[2];
  const float* Wc = (const float*)d_in[3];
  const float* bc = (const float*)d_in[4];
  const float* Wa = (const float*)d_in[5];
  const float* ba = (const float*)d_in[6];
  const float* Wp = (const float*)d_in[7];
  const float* bp = (const float*)d_in[8];
  const int*  step = (const int*)d_in[9];
  float* out = (float*)d_out;

  float* ws = (float*)d_ws;
  float* glb     = ws;                    // 64*512
  float* ave     = glb + 64*512;          // 64*512
  float* afx     = ave + 64*512;          // 64*17*128
  float* sx      = afx + 64*NA*F;         // 64*17
  float* Wpy     = sx + 64*NA;            // 128*128
  float* M1      = Wpy + F*F;             // 128*128
  float* czc     = M1 + F*F;              // 64*128
  float* vz      = czc + 64*F;            // 64*128
  float* szc     = vz + 64*F;             // 64
  float* rowsum  = szc + 64;              // 64*17
  float* tpart   = rowsum + 64*NA;        // 8*64*17*128
  float* afz     = tpart + 8*64*NA*F;     // 64*17*128
  float* szv     = afz + 64*NA*F;         // 64*17
  float* ucj     = szv + 64*NA;           // 64*17*2048
  float* pmax    = ucj + (size_t)64*NA*CN;// 64*17*8
  // total ~15 MiB of ws

  k0a_wpy<<<F,F,0,stream>>>(Wp, Wc, Wpy);
  k0b_m1<<<F,F,0,stream>>>(Wc, Wpy, M1);
  k1_reduce<<<dim3(128,64),256,0,stream>>>(nf, glb, ave);
  k2_prep<<<64,256,0,stream>>>(nf, Wg,bg,Wc,bc,Wa,ba,Wp,bp, Wpy, glb,ave, afx,sx,czc,vz,szc);
  k3_scores<<<dim3(8,64),256,0,stream>>>(nf, afx, sx, ucj, pmax);
  k4_softmax<<<dim3(NA,64),256,0,stream>>>(ucj, pmax, rowsum);
  k5_taccum<<<dim3(8,64),256,0,stream>>>(nf, ucj, tpart);
  k5b_final<<<dim3(NA,64),128,0,stream>>>(M1, tpart, rowsum, czc, vz, szc, afz, szv);
  k6_out<<<dim3(8,64),256,0,stream>>>(nf, afz, szv, step, out);
}